// Round 8
// baseline (112.939 us; speedup 1.0000x reference)
//
#include <hip/hip_runtime.h>
#include <hip/hip_bf16.h>
#include <math.h>

#define BB   32
#define CC   512
#define NPIX 1600
#define KK   64
#define NT   25        // 64-wide n-tiles in pass A
#define EPSF 1e-12f

typedef __attribute__((ext_vector_type(8))) short bf16x8;
typedef __attribute__((ext_vector_type(4))) float f32x4;
#define MFMA16 __builtin_amdgcn_mfma_f32_16x16x32_bf16

__device__ __forceinline__ ushort f2bf(float f) {
    __hip_bfloat16 h = __float2bfloat16(f);       // RNE, HW cvt
    return *reinterpret_cast<ushort*>(&h);
}
__device__ __forceinline__ uint pk2bf(float a, float b) {
    return (uint)f2bf(a) | ((uint)f2bf(b) << 16);
}

// ---------------------------------------------------------------------------
// k_wprep: w_bf16[k][c] = bf16(w[k][c])   (one-time, 64 KB out)
// ---------------------------------------------------------------------------
__global__ __launch_bounds__(256) void k_wprep(const float* __restrict__ w,
                                               ushort* __restrict__ wb) {
    int i = blockIdx.x * 256 + threadIdx.x;       // over KK*CC/2 = 16384 pairs
    float2 v = *(const float2*)&w[(size_t)i * 2];
    ((uint*)wb)[i] = pk2bf(v.x, v.y);
}

// ---------------------------------------------------------------------------
// k_gemm1m: per (64n tile, b), LDS-free MFMA GEMM + fused softmax:
//   logits[k][n] = sum_c w[k,c] x[b,c,n]; ssq from the same loaded values;
//   a' = softmax_k(logits*invn)*invn -> a_t[b][k][n] bf16; asum_p.
// Fragment feeds (layout verified by R7):
//   A (w): uint4 from w_bf16[rk*CC + cbase]            (L1/L2-resident)
//   B (x^T): 8 scalar dwords x[b][cbase+j][n0+rn] + HW cvt
// D element: k = kf*16 + (lane>>4)*4 + r,  n = wv*16 + (lane&15).
// No LDS/barriers in the hot loop.
// ---------------------------------------------------------------------------
__global__ __launch_bounds__(256) void k_gemm1m(const float* __restrict__ x,
                                                const ushort* __restrict__ wb,
                                                ushort* __restrict__ a_t,
                                                float* __restrict__ asum_p) {
    int tile = blockIdx.x, b = blockIdx.y;
    int n0 = tile * 64;
    int t = threadIdx.x, lane = t & 63, wv = t >> 6;
    int nlo = lane & 15, khi = lane >> 4;
    int rn = wv * 16 + nlo;                        // this lane's n-column
    const float* xb = x + (size_t)b * CC * NPIX + n0 + rn;
    __shared__ float asw[4 * 64];
    f32x4 acc[4] = {};
    float ss = 0.f;

    for (int it = 0; it < 16; ++it) {
        int cbase = it * 32 + khi * 8;
        float f[8];
#pragma unroll
        for (int j = 0; j < 8; ++j)
            f[j] = xb[(size_t)(cbase + j) * NPIX];
        uint4 bp;
        bp.x = pk2bf(f[0], f[1]); bp.y = pk2bf(f[2], f[3]);
        bp.z = pk2bf(f[4], f[5]); bp.w = pk2bf(f[6], f[7]);
        bf16x8 bfr = *reinterpret_cast<bf16x8*>(&bp);
#pragma unroll
        for (int j = 0; j < 8; ++j) ss = fmaf(f[j], f[j], ss);
#pragma unroll
        for (int kf = 0; kf < 4; ++kf) {
            int rk = kf * 16 + nlo;
            bf16x8 afr = *(const bf16x8*)&wb[(size_t)rk * CC + cbase];
            acc[kf] = MFMA16(afr, bfr, acc[kf], 0, 0, 0);
        }
    }

    // ssq: combine the 4 khi groups (same n) -> invn for this lane's n
    ss += __shfl_xor(ss, 16);
    ss += __shfl_xor(ss, 32);
    float invl = 1.f / fmaxf(sqrtf(ss), EPSF);

    // softmax over k (lane holds 16 k's for one n; combine khi groups)
    float lv[4][4];
    float mm = -1e30f;
#pragma unroll
    for (int kf = 0; kf < 4; ++kf)
#pragma unroll
        for (int r = 0; r < 4; ++r) {
            lv[kf][r] = acc[kf][r] * invl;
            mm = fmaxf(mm, lv[kf][r]);
        }
    mm = fmaxf(mm, __shfl_xor(mm, 16));
    mm = fmaxf(mm, __shfl_xor(mm, 32));
    float ev[4][4], s = 0.f;
#pragma unroll
    for (int kf = 0; kf < 4; ++kf)
#pragma unroll
        for (int r = 0; r < 4; ++r) {
            ev[kf][r] = expf(lv[kf][r] - mm);
            s += ev[kf][r];
        }
    s += __shfl_xor(s, 16);
    s += __shfl_xor(s, 32);
    float sd = 1.f / s;

    // asum partials (unscaled a): reduce over the wave's 16 n
    float av[4][4];
#pragma unroll
    for (int kf = 0; kf < 4; ++kf)
#pragma unroll
        for (int r = 0; r < 4; ++r) av[kf][r] = ev[kf][r] * sd;
#pragma unroll
    for (int off = 1; off < 16; off <<= 1)
#pragma unroll
        for (int kf = 0; kf < 4; ++kf)
#pragma unroll
            for (int r = 0; r < 4; ++r) av[kf][r] += __shfl_xor(av[kf][r], off);
    if (nlo == 0) {
#pragma unroll
        for (int kf = 0; kf < 4; ++kf)
#pragma unroll
            for (int r = 0; r < 4; ++r)
                asw[wv * 64 + kf * 16 + khi * 4 + r] = av[kf][r];
    }

    // a' = a * invn -> a_t[b][k][n] bf16
    ushort* ab = a_t + (size_t)b * KK * NPIX;
#pragma unroll
    for (int kf = 0; kf < 4; ++kf)
#pragma unroll
        for (int r = 0; r < 4; ++r) {
            int k = kf * 16 + khi * 4 + r;
            ab[(size_t)k * NPIX + n0 + rn] = f2bf(ev[kf][r] * sd * invl);
        }
    __syncthreads();
    if (t < 64) {
        float a4 = asw[t] + asw[64 + t] + asw[128 + t] + asw[192 + t];
        asum_p[((size_t)b * KK + t) * NT + tile] = a4;
    }
}

// ---------------------------------------------------------------------------
// k_vladm: part[s][b][k][c] = sum_{n in chunk} a'[k,n] * x[c,n]   (MFMA)
// LDS-free: A-frag = uint4 from a_t[b][k][n] (n-contig);
//           B-frag = 2x float4 from x[b][c][n] (n-contig) + HW cvt.
// D element: k = kf*16 + (lane>>4)*4 + r,  c = c0 + wv*16 + (lane&15).
// ---------------------------------------------------------------------------
__global__ __launch_bounds__(256) void k_vladm(const ushort* __restrict__ a_t,
                                               const float* __restrict__ x,
                                               float* __restrict__ part,
                                               int nchunk) {
    int c0 = blockIdx.x * 64;
    int s  = blockIdx.y;
    int b  = blockIdx.z;
    int t = threadIdx.x, lane = t & 63, wv = t >> 6;
    int clo = lane & 15, nhi = lane >> 4;
    int rc = wv * 16 + clo;                        // this lane's c-column
    const ushort* ab = a_t + (size_t)b * KK * NPIX;
    const float*  xr = x + (size_t)b * CC * NPIX + (size_t)(c0 + rc) * NPIX;
    f32x4 acc[4] = {};
    int nbase = s * nchunk, niters = nchunk / 32;

    for (int it = 0; it < niters; ++it) {
        int nb = nbase + it * 32 + nhi * 8;
        float4 x0 = *(const float4*)&xr[nb];
        float4 x1 = *(const float4*)&xr[nb + 4];
        uint4 bp;
        bp.x = pk2bf(x0.x, x0.y); bp.y = pk2bf(x0.z, x0.w);
        bp.z = pk2bf(x1.x, x1.y); bp.w = pk2bf(x1.z, x1.w);
        bf16x8 bfr = *reinterpret_cast<bf16x8*>(&bp);
#pragma unroll
        for (int kf = 0; kf < 4; ++kf) {
            int rk = kf * 16 + clo;
            bf16x8 afr = *(const bf16x8*)&ab[(size_t)rk * NPIX + nb];
            acc[kf] = MFMA16(afr, bfr, acc[kf], 0, 0, 0);
        }
    }

#pragma unroll
    for (int kf = 0; kf < 4; ++kf)
#pragma unroll
        for (int r = 0; r < 4; ++r) {
            int k = kf * 16 + nhi * 4 + r;
            part[(((size_t)s * BB + b) * KK + k) * CC + c0 + rc] = acc[kf][r];
        }
}

// ---------------------------------------------------------------------------
// k_intra: sum ns partials, asum from tile-partials, subtract asum*cent,
// intra-normalize per (b,k), accumulate per-b sum of squares.
// ---------------------------------------------------------------------------
__global__ __launch_bounds__(256) void k_intra(const float* __restrict__ part, int ns,
                                               const float* __restrict__ asum_p,
                                               const float* __restrict__ cent,
                                               float* __restrict__ out,
                                               float* __restrict__ bsum) {
    int row = blockIdx.x;                          // b*KK + k
    int b = row >> 6, k = row & 63;
    int t = threadIdx.x;
    float v0 = 0.f, v1 = 0.f;
    for (int s2 = 0; s2 < ns; ++s2) {
        const float* p = part + (((size_t)s2 * BB + b) * KK + k) * CC;
        v0 += p[t];
        v1 += p[t + 256];
    }
    float as = 0.f;
#pragma unroll
    for (int i = 0; i < NT; ++i) as += asum_p[(size_t)row * NT + i];
    v0 -= as * cent[k * CC + t];
    v1 -= as * cent[k * CC + t + 256];
    float ssq = v0 * v0 + v1 * v1;
#pragma unroll
    for (int off = 32; off; off >>= 1) ssq += __shfl_down(ssq, off, 64);
    __shared__ float red[4];
    __shared__ float s_inv;
    if ((t & 63) == 0) red[t >> 6] = ssq;
    __syncthreads();
    if (t == 0) {
        float sm = red[0] + red[1] + red[2] + red[3];
        float inv = 1.f / fmaxf(sqrtf(sm), EPSF);
        s_inv = inv;
        atomicAdd(&bsum[b], sm * inv * inv);
    }
    __syncthreads();
    float inv = s_inv;
    out[(size_t)row * CC + t]       = v0 * inv;
    out[(size_t)row * CC + t + 256] = v1 * inv;
}

// ---------------------------------------------------------------------------
__global__ __launch_bounds__(256) void k_scale(float* __restrict__ out,
                                               const float* __restrict__ bsum) {
    int idx = blockIdx.x * 256 + threadIdx.x;      // B*K*C exact
    int b = idx >> 15;                             // K*C = 32768
    out[idx] *= 1.f / fmaxf(sqrtf(bsum[b]), EPSF);
}

// ---------------------------------------------------------------------------
extern "C" void kernel_launch(void* const* d_in, const int* in_sizes, int n_in,
                              void* d_out, int out_size, void* d_ws, size_t ws_size,
                              hipStream_t stream) {
    const float* x    = (const float*)d_in[0];   // [B,C,H,W]
    const float* cent = (const float*)d_in[1];   // [K,C]
    const float* w    = (const float*)d_in[2];   // [K,C]
    float* out = (float*)d_out;

    char* wsb = (char*)d_ws;
    const size_t oa_at   = 0;                                  // bf16 B*K*N = 6,553,600 B
    const size_t oa_wb   = oa_at + (size_t)BB * KK * NPIX * 2; // bf16 K*C   =    65,536 B
    const size_t oa_asum = oa_wb + (size_t)KK * CC * 2;        // f32 B*K*NT =   204,800 B
    const size_t oa_bsum = oa_asum + (size_t)BB * KK * NT * 4; //                    128 B
    const size_t oa_part = oa_bsum + 128;
    ushort* a_t   = (ushort*)(wsb + oa_at);
    ushort* wb    = (ushort*)(wsb + oa_wb);
    float* asum_p = (float*)(wsb + oa_asum);
    float* bsum   = (float*)(wsb + oa_bsum);

    // pick ns with nchunk = 1600/ns a multiple of 32: {5, 2, 1}
    const size_t pbytes = (size_t)BB * KK * CC * 4;            // 4 MB per partial
    int ns = 0;
    const int cand[3] = {5, 2, 1};
    for (int i = 0; i < 3; ++i) {
        if (oa_part + (size_t)cand[i] * pbytes <= ws_size) { ns = cand[i]; break; }
    }
    float* part = (ns > 0) ? (float*)(wsb + oa_part) : out;    // ns=1 fallback -> d_out
    if (ns == 0) ns = 1;
    int nchunk = NPIX / ns;

    hipMemsetAsync(bsum, 0, BB * sizeof(float), stream);

    k_wprep <<<dim3((KK * CC / 2) / 256), 256, 0, stream>>>(w, wb);
    k_gemm1m<<<dim3(NT, BB), 256, 0, stream>>>(x, wb, a_t, asum_p);
    k_vladm <<<dim3(CC / 64, ns, BB), 256, 0, stream>>>(a_t, x, part, nchunk);
    k_intra <<<dim3(BB * KK), 256, 0, stream>>>(part, ns, asum_p, cent, out, bsum);
    k_scale <<<dim3((BB * KK * CC) / 256), 256, 0, stream>>>(out, bsum);
}